// Round 6
// baseline (5515.437 us; speedup 1.0000x reference)
//
#include <hip/hip_runtime.h>
#include <hip/hip_cooperative_groups.h>
#include <cstddef>

namespace cg = cooperative_groups;

#define NS 26

typedef short bf16x8 __attribute__((ext_vector_type(8)));
typedef float f32x4 __attribute__((ext_vector_type(4)));

__device__ __forceinline__ float tanh_fast(float x) { return 1.f - 2.f / (__expf(2.f * x) + 1.f); }
__device__ __forceinline__ float sigf(float x) { return 1.f / (1.f + __expf(-x)); }
__device__ __forceinline__ unsigned short f2bf(float x) {
    unsigned int u = __float_as_uint(x);
    return (unsigned short)((u + 0x7FFFu + ((u >> 16) & 1u)) >> 16);
}

// ---------------- setup converts (unchanged from R4) ----------------
__global__ __launch_bounds__(256) void conv_f32_bf16(const float* __restrict__ s,
                                                     unsigned short* __restrict__ d, int n4) {
    int i = blockIdx.x * 256 + threadIdx.x;
    if (i >= n4) return;
    float4 v = ((const float4*)s)[i];
    ushort4 o; o.x = f2bf(v.x); o.y = f2bf(v.y); o.z = f2bf(v.z); o.w = f2bf(v.w);
    ((ushort4*)d)[i] = o;
}
__global__ __launch_bounds__(256) void conv_w_perm(const float* __restrict__ src, int stride,
                                                   unsigned short* __restrict__ dst) {
    int i = blockIdx.x * 256 + threadIdx.x;
    int np = i >> 6, k8 = (i & 63) << 3;
    int h = np >> 2, g = np & 3;
    const float* p = src + (size_t)(g * 512 + h) * stride + k8;
    float4 v0 = *(const float4*)p, v1 = *(const float4*)(p + 4);
    ushort4 o0, o1;
    o0.x = f2bf(v0.x); o0.y = f2bf(v0.y); o0.z = f2bf(v0.z); o0.w = f2bf(v0.w);
    o1.x = f2bf(v1.x); o1.y = f2bf(v1.y); o1.z = f2bf(v1.z); o1.w = f2bf(v1.w);
    *(ushort4*)(dst + (size_t)np * 512 + k8) = o0;
    *(ushort4*)(dst + (size_t)np * 512 + k8 + 4) = o1;
}
__global__ __launch_bounds__(256) void conv_wtok(const float* __restrict__ W_ih,
                                                 float* __restrict__ wtp) {
    int i = blockIdx.x * 256 + threadIdx.x;
    if (i >= 96 * 2048) return;
    int t = i >> 11, np = i & 2047;
    int h = np >> 2, g = np & 3;
    wtp[i] = W_ih[(size_t)(g * 512 + h) * 608 + 512 + t];
}
__global__ __launch_bounds__(256) void bias_perm(const float* __restrict__ bi,
                                                 const float* __restrict__ bh,
                                                 float* __restrict__ o) {
    int i = blockIdx.x * 256 + threadIdx.x;
    int h = i >> 2, g = i & 3, n = g * 512 + h;
    o[i] = bi[n] + bh[n];
}

// ---------------------------------------------------------------------------
// bf16 NT MFMA GEMM (unchanged from R4)
// ---------------------------------------------------------------------------
template <int MODE, int SWZ>
__global__ __launch_bounds__(256) void gemm_bf16(
    const unsigned short* __restrict__ A, int lda,
    const unsigned short* __restrict__ B, int ldb,
    void* __restrict__ Cout, int ldc,
    const float* __restrict__ bias, int K, int Nreal)
{
    __shared__ unsigned short As[2][64][72];
    __shared__ unsigned short Bs[2][64][72];
    const int tid = threadIdx.x;
    int bm, bn;
    if (SWZ == 1) {
        const int l = blockIdx.x + (blockIdx.y << 9);
        const int cc = l & 7, k = l >> 3;
        bm = ((cc << 6) + (k >> 3)) << 6;
        bn = (k & 7) << 6;
    } else {
        bm = blockIdx.y << 6;
        bn = blockIdx.x << 6;
    }
    const int w = tid >> 6, lane = tid & 63;
    const int wr = w >> 1, wc = w & 1;
    const int srow = tid >> 2, schunk = (tid & 3) << 4;
    int brow = bn + srow;
    if (MODE == 3) brow = min(brow, Nreal - 1);
    const unsigned short* Ap = A + (size_t)(bm + srow) * lda + schunk;
    const unsigned short* Bp = B + (size_t)brow * ldb + schunk;
    const int fr = lane & 15, fq = lane >> 4;

    uint4 ra0, ra1, rb0, rb1;
    f32x4 acc[2][2];
#pragma unroll
    for (int i = 0; i < 2; i++)
#pragma unroll
        for (int j = 0; j < 2; j++) acc[i][j] = f32x4{0.f, 0.f, 0.f, 0.f};

    const int NTk = K >> 6;
#define LOADR(t) { ra0 = *(const uint4*)(Ap + ((t) << 6)); ra1 = *(const uint4*)(Ap + ((t) << 6) + 8); \
                   rb0 = *(const uint4*)(Bp + ((t) << 6)); rb1 = *(const uint4*)(Bp + ((t) << 6) + 8); }
#define WRITEB(cb) { *(uint4*)&As[cb][srow][schunk] = ra0; *(uint4*)&As[cb][srow][schunk + 8] = ra1; \
                     *(uint4*)&Bs[cb][srow][schunk] = rb0; *(uint4*)&Bs[cb][srow][schunk + 8] = rb1; }
    LOADR(0); WRITEB(0);
    LOADR(1);
    __syncthreads();
    for (int t = 0; t < NTk; t++) {
        const int cb = t & 1;
        if (t + 1 < NTk) WRITEB(cb ^ 1);
        if (t + 2 < NTk) LOADR(t + 2);
        bf16x8 af[2][2], bfr[2][2];
#pragma unroll
        for (int fi = 0; fi < 2; fi++)
#pragma unroll
            for (int ks = 0; ks < 2; ks++) {
                af[fi][ks]  = *(const bf16x8*)&As[cb][(wr << 5) + (fi << 4) + fr][(ks << 5) + (fq << 3)];
                bfr[fi][ks] = *(const bf16x8*)&Bs[cb][(wc << 5) + (fi << 4) + fr][(ks << 5) + (fq << 3)];
            }
#pragma unroll
        for (int fi = 0; fi < 2; fi++)
#pragma unroll
            for (int fj = 0; fj < 2; fj++)
#pragma unroll
                for (int ks = 0; ks < 2; ks++)
                    acc[fi][fj] = __builtin_amdgcn_mfma_f32_16x16x32_bf16(
                        af[fi][ks], bfr[fj][ks], acc[fi][fj], 0, 0, 0);
        __syncthreads();
    }
#undef LOADR
#undef WRITEB
#pragma unroll
    for (int fi = 0; fi < 2; fi++) {
        const int mbase = bm + (wr << 5) + (fi << 4) + (fq << 2);
#pragma unroll
        for (int fj = 0; fj < 2; fj++) {
            const int n = bn + (wc << 5) + (fj << 4) + fr;
            f32x4 v = acc[fi][fj];
            if (MODE == 0) {
                unsigned short* C = (unsigned short*)Cout;
#pragma unroll
                for (int r = 0; r < 4; r++) C[(size_t)(mbase + r) * ldc + n] = f2bf(v[r]);
            } else {
                if (n < Nreal) {
                    float* C = (float*)Cout;
                    const float bb = bias[n];
#pragma unroll
                    for (int r = 0; r < 4; r++) C[(size_t)(mbase + r) * ldc + n] = v[r] + bb;
                }
            }
        }
    }
}

// ---------------------------------------------------------------------------
// Standalone gates_lstm (unchanged from R4) — used by the fallback path.
// ---------------------------------------------------------------------------
__global__ __launch_bounds__(256) void gates_lstm(
    const unsigned short* __restrict__ ctx,
    const unsigned short* __restrict__ hprev,
    const unsigned short* __restrict__ Wgi,
    const unsigned short* __restrict__ Wgh,
    const float* __restrict__ bsum_p,
    const float* __restrict__ Wtok_p,
    const int* __restrict__ text, int sstep,
    float* __restrict__ c,
    unsigned short* __restrict__ hs,
    unsigned short* __restrict__ hnew)
{
    __shared__ __align__(16) char smem[36864];
    unsigned short (*As)[64][72] = (unsigned short(*)[64][72])smem;
    unsigned short (*Bs)[64][72] = (unsigned short(*)[64][72])(smem + 18432);
    float (*gls)[68] = (float(*)[68])smem;

    const int tid = threadIdx.x;
    const int l = blockIdx.x + (blockIdx.y << 5);
    const int cc = l & 7, kq = l >> 3;
    const int nblk = (cc << 2) + (kq >> 3);
    const int m0 = (kq & 7) << 6;
    const int bn_ = nblk << 6;
    const int w = tid >> 6, lane = tid & 63;
    const int wr = w >> 1, wc = w & 1;
    const int srow = tid >> 2, schunk = (tid & 3) << 4;
    const int fr = lane & 15, fq = lane >> 4;

    const unsigned short* Ac = ctx   + (size_t)(m0 + srow) * 512 + schunk;
    const unsigned short* Ah = hprev + (size_t)(m0 + srow) * 512 + schunk;
    const unsigned short* Bi = Wgi + (size_t)(bn_ + srow) * 512 + schunk;
    const unsigned short* Bh = Wgh + (size_t)(bn_ + srow) * 512 + schunk;

    uint4 ra0, ra1, rb0, rb1;
    f32x4 acc[2][2];
#pragma unroll
    for (int i = 0; i < 2; i++)
#pragma unroll
        for (int j = 0; j < 2; j++) acc[i][j] = f32x4{0.f, 0.f, 0.f, 0.f};

#define GLOAD(t) { const int tt = (t); \
    const unsigned short* ap = (tt < 8) ? Ac + (tt << 6) : Ah + ((tt - 8) << 6); \
    const unsigned short* bp = (tt < 8) ? Bi + (tt << 6) : Bh + ((tt - 8) << 6); \
    ra0 = *(const uint4*)ap; ra1 = *(const uint4*)(ap + 8); \
    rb0 = *(const uint4*)bp; rb1 = *(const uint4*)(bp + 8); }
#define WRITEB(cb) { *(uint4*)&As[cb][srow][schunk] = ra0; *(uint4*)&As[cb][srow][schunk + 8] = ra1; \
                     *(uint4*)&Bs[cb][srow][schunk] = rb0; *(uint4*)&Bs[cb][srow][schunk + 8] = rb1; }
    GLOAD(0); WRITEB(0);
    GLOAD(1);
    __syncthreads();
    for (int t = 0; t < 16; t++) {
        const int cb = t & 1;
        if (t + 1 < 16) WRITEB(cb ^ 1);
        if (t + 2 < 16) GLOAD(t + 2);
        bf16x8 af[2][2], bfr[2][2];
#pragma unroll
        for (int fi = 0; fi < 2; fi++)
#pragma unroll
            for (int ks = 0; ks < 2; ks++) {
                af[fi][ks]  = *(const bf16x8*)&As[cb][(wr << 5) + (fi << 4) + fr][(ks << 5) + (fq << 3)];
                bfr[fi][ks] = *(const bf16x8*)&Bs[cb][(wc << 5) + (fi << 4) + fr][(ks << 5) + (fq << 3)];
            }
#pragma unroll
        for (int fi = 0; fi < 2; fi++)
#pragma unroll
            for (int fj = 0; fj < 2; fj++)
#pragma unroll
                for (int ks = 0; ks < 2; ks++)
                    acc[fi][fj] = __builtin_amdgcn_mfma_f32_16x16x32_bf16(
                        af[fi][ks], bfr[fj][ks], acc[fi][fj], 0, 0, 0);
        __syncthreads();
    }
#undef GLOAD
#undef WRITEB
#pragma unroll
    for (int fi = 0; fi < 2; fi++)
#pragma unroll
        for (int fj = 0; fj < 2; fj++)
#pragma unroll
            for (int r = 0; r < 4; r++)
                gls[(wr << 5) + (fi << 4) + (fq << 2) + r][(wc << 5) + (fj << 4) + fr] = acc[fi][fj][r];
    __syncthreads();

    const int hbase = nblk << 4;
#pragma unroll
    for (int p = 0; p < 4; p++) {
        const int idx = (p << 8) + tid;
        const int ml = idx >> 4, hl = idx & 15;
        const int mg = m0 + ml, hg = hbase + hl;
        const int tok = text[mg * NS + sstep];
        const float4 gq = *(const float4*)&gls[ml][hl << 2];
        const float4 bq = *(const float4*)&bsum_p[bn_ + (hl << 2)];
        const float4 wq = *(const float4*)&Wtok_p[(size_t)tok * 2048 + bn_ + (hl << 2)];
        const float i_ = sigf(gq.x + bq.x + wq.x);
        const float f_ = sigf(gq.y + bq.y + wq.y);
        const float g_ = tanh_fast(gq.z + bq.z + wq.z);
        const float o_ = sigf(gq.w + bq.w + wq.w);
        const size_t ci = (size_t)mg * 512 + hg;
        const float cn = fmaf(f_, c[ci], i_ * g_);
        c[ci] = cn;
        const unsigned short hv = f2bf(o_ * tanh_fast(cn));
        hs[((size_t)mg * NS + sstep) * 512 + hg] = hv;
        hnew[ci] = hv;
    }
}

// ---------------------------------------------------------------------------
// Standalone attention (unchanged from R4) — used by the fallback path.
// ---------------------------------------------------------------------------
__global__ __launch_bounds__(256) void attn_kernel(
    const unsigned short* __restrict__ H_proj,
    const float* __restrict__ ph,
    const float* __restrict__ w_score,
    const unsigned short* __restrict__ batch_H,
    unsigned short* __restrict__ ctx)
{
    __shared__ float s_ph[512];
    __shared__ float s_w[512];
    __shared__ float s_e[64];
    __shared__ float s_al[64];
    const int b = blockIdx.x;
    const int tid = threadIdx.x;
    s_ph[tid] = ph[b * 512 + tid];
    s_ph[tid + 256] = ph[b * 512 + 256 + tid];
    s_w[tid] = w_score[tid];
    s_w[tid + 256] = w_score[tid + 256];
    __syncthreads();

    const int w = tid >> 6, lane = tid & 63;
    for (int t = w; t < 64; t += 4) {
        const uint4 hv = *(const uint4*)(H_proj + ((size_t)b * 64 + t) * 512 + lane * 8);
        const int h0 = lane * 8;
        unsigned int ua[4] = {hv.x, hv.y, hv.z, hv.w};
        float acc = 0.f;
#pragma unroll
        for (int j = 0; j < 4; j++) {
            const float e0 = __uint_as_float(ua[j] << 16);
            const float e1 = __uint_as_float(ua[j] & 0xffff0000u);
            acc += tanh_fast(e0 + s_ph[h0 + 2 * j]) * s_w[h0 + 2 * j];
            acc += tanh_fast(e1 + s_ph[h0 + 2 * j + 1]) * s_w[h0 + 2 * j + 1];
        }
#pragma unroll
        for (int off = 32; off; off >>= 1) acc += __shfl_xor(acc, off);
        if (lane == 0) s_e[t] = acc;
    }
    __syncthreads();
    if (tid < 64) {
        float m = -1e30f;
        for (int t = 0; t < 64; ++t) m = fmaxf(m, s_e[t]);
        float sum = 0.f;
        for (int t = 0; t < 64; ++t) sum += __expf(s_e[t] - m);
        s_al[tid] = __expf(s_e[tid] - m) / sum;
    }
    __syncthreads();
    const unsigned int* bHp = (const unsigned int*)(batch_H + (size_t)b * 64 * 512);
    float a0 = 0.f, a1 = 0.f;
    for (int t = 0; t < 64; ++t) {
        const unsigned int u = bHp[t * 256 + tid];
        const float al = s_al[t];
        a0 = fmaf(al, __uint_as_float(u << 16), a0);
        a1 = fmaf(al, __uint_as_float(u & 0xffff0000u), a1);
    }
    const unsigned int o = ((unsigned int)f2bf(a1) << 16) | (unsigned int)f2bf(a0);
    ((unsigned int*)(ctx + (size_t)b * 512))[tid] = o;
}

// ---------------------------------------------------------------------------
// Cooperative step loop: R4 phase bodies VERBATIM, launches -> grid.sync().
// 512 blocks x 256 thr, LDS 36864 (2 blocks/CU).
// ---------------------------------------------------------------------------
__global__ __launch_bounds__(256, 2) void step_loop(
    const unsigned short* Hproj, const unsigned short* bH,
    const unsigned short* Wh2hb, const float* b_h2h, const float* w_score,
    const unsigned short* Wgi, const unsigned short* Wgh,
    const float* bsum_p, const float* Wtok_p, const int* text,
    unsigned short* hbuf0, unsigned short* hbuf1, unsigned short* ctxb,
    float* phb, float* cst, unsigned short* hs)
{
    cg::grid_group grid = cg::this_grid();
    __shared__ __align__(16) char smem[36864];
    unsigned short (*As)[64][72] = (unsigned short(*)[64][72])smem;
    unsigned short (*Bs)[64][72] = (unsigned short(*)[64][72])(smem + 18432);
    float (*gls)[68] = (float(*)[68])smem;
    float* s_ph = (float*)smem;
    float* s_w  = (float*)(smem + 2048);
    float* s_e  = (float*)(smem + 4096);
    float* s_al = (float*)(smem + 4352);

    const int bid = blockIdx.x, tid = threadIdx.x;
    const int w = tid >> 6, lane = tid & 63;
    const int fr = lane & 15, fq = lane >> 4;

    for (int s = 0; s < NS; s++) {
        const unsigned short* hprev = (s & 1) ? hbuf0 : hbuf1;
        unsigned short* hcur = (s & 1) ? hbuf1 : hbuf0;

        // ===== Phase A (verbatim gemm_bf16<3,0> body; grid (8,8) -> bid<64) =====
        if (bid < 64) {
            const int bm = (bid >> 3) << 6, bn = (bid & 7) << 6;
            const int wr = w >> 1, wc = w & 1;
            const int srow = tid >> 2, schunk = (tid & 3) << 4;
            const unsigned short* Ap = hprev + (size_t)(bm + srow) * 512 + schunk;
            const unsigned short* Bp = Wh2hb + (size_t)(bn + srow) * 512 + schunk;
            uint4 ra0, ra1, rb0, rb1;
            f32x4 acc[2][2];
#pragma unroll
            for (int i = 0; i < 2; i++)
#pragma unroll
                for (int j = 0; j < 2; j++) acc[i][j] = f32x4{0.f, 0.f, 0.f, 0.f};
#define LOADRA(t) { ra0 = *(const uint4*)(Ap + ((t) << 6)); ra1 = *(const uint4*)(Ap + ((t) << 6) + 8); \
                    rb0 = *(const uint4*)(Bp + ((t) << 6)); rb1 = *(const uint4*)(Bp + ((t) << 6) + 8); }
#define WRITEBA(cb) { *(uint4*)&As[cb][srow][schunk] = ra0; *(uint4*)&As[cb][srow][schunk + 8] = ra1; \
                      *(uint4*)&Bs[cb][srow][schunk] = rb0; *(uint4*)&Bs[cb][srow][schunk + 8] = rb1; }
            LOADRA(0); WRITEBA(0);
            LOADRA(1);
            __syncthreads();
            for (int t = 0; t < 8; t++) {
                const int cb = t & 1;
                if (t + 1 < 8) WRITEBA(cb ^ 1);
                if (t + 2 < 8) LOADRA(t + 2);
                bf16x8 af[2][2], bfr[2][2];
#pragma unroll
                for (int fi = 0; fi < 2; fi++)
#pragma unroll
                    for (int ks = 0; ks < 2; ks++) {
                        af[fi][ks]  = *(const bf16x8*)&As[cb][(wr << 5) + (fi << 4) + fr][(ks << 5) + (fq << 3)];
                        bfr[fi][ks] = *(const bf16x8*)&Bs[cb][(wc << 5) + (fi << 4) + fr][(ks << 5) + (fq << 3)];
                    }
#pragma unroll
                for (int fi = 0; fi < 2; fi++)
#pragma unroll
                    for (int fj = 0; fj < 2; fj++)
#pragma unroll
                        for (int ks = 0; ks < 2; ks++)
                            acc[fi][fj] = __builtin_amdgcn_mfma_f32_16x16x32_bf16(
                                af[fi][ks], bfr[fj][ks], acc[fi][fj], 0, 0, 0);
                __syncthreads();
            }
#undef LOADRA
#undef WRITEBA
#pragma unroll
            for (int fi = 0; fi < 2; fi++) {
                const int mbase = bm + (wr << 5) + (fi << 4) + (fq << 2);
#pragma unroll
                for (int fj = 0; fj < 2; fj++) {
                    const int n = bn + (wc << 5) + (fj << 4) + fr;
                    const float bb = b_h2h[n];
#pragma unroll
                    for (int r = 0; r < 4; r++)
                        phb[(size_t)(mbase + r) * 512 + n] = acc[fi][fj][r] + bb;
                }
            }
        }
        grid.sync();

        // ===== Phase B (verbatim attn_kernel body; b = bid) =====
        {
            const int b = bid;
            s_ph[tid] = phb[b * 512 + tid];
            s_ph[tid + 256] = phb[b * 512 + 256 + tid];
            s_w[tid] = w_score[tid];
            s_w[tid + 256] = w_score[tid + 256];
            __syncthreads();
            for (int t = w; t < 64; t += 4) {
                const uint4 hv = *(const uint4*)(Hproj + ((size_t)b * 64 + t) * 512 + lane * 8);
                const int h0 = lane * 8;
                unsigned int ua[4] = {hv.x, hv.y, hv.z, hv.w};
                float acc = 0.f;
#pragma unroll
                for (int j = 0; j < 4; j++) {
                    const float e0 = __uint_as_float(ua[j] << 16);
                    const float e1 = __uint_as_float(ua[j] & 0xffff0000u);
                    acc += tanh_fast(e0 + s_ph[h0 + 2 * j]) * s_w[h0 + 2 * j];
                    acc += tanh_fast(e1 + s_ph[h0 + 2 * j + 1]) * s_w[h0 + 2 * j + 1];
                }
#pragma unroll
                for (int off = 32; off; off >>= 1) acc += __shfl_xor(acc, off);
                if (lane == 0) s_e[t] = acc;
            }
            __syncthreads();
            if (tid < 64) {
                float m = -1e30f;
                for (int t = 0; t < 64; ++t) m = fmaxf(m, s_e[t]);
                float sum = 0.f;
                for (int t = 0; t < 64; ++t) sum += __expf(s_e[t] - m);
                s_al[tid] = __expf(s_e[tid] - m) / sum;
            }
            __syncthreads();
            const unsigned int* bHp = (const unsigned int*)(bH + (size_t)b * 64 * 512);
            float a0 = 0.f, a1 = 0.f;
            for (int t = 0; t < 64; ++t) {
                const unsigned int u = bHp[t * 256 + tid];
                const float al = s_al[t];
                a0 = fmaf(al, __uint_as_float(u << 16), a0);
                a1 = fmaf(al, __uint_as_float(u & 0xffff0000u), a1);
            }
            const unsigned int o = ((unsigned int)f2bf(a1) << 16) | (unsigned int)f2bf(a0);
            ((unsigned int*)(ctxb + (size_t)b * 512))[tid] = o;
        }
        grid.sync();

        // ===== Phase C (verbatim gates_lstm body; l = bid < 256) =====
        if (bid < 256) {
            const int l = bid;
            const int cc = l & 7, kq = l >> 3;
            const int nblk = (cc << 2) + (kq >> 3);
            const int m0 = (kq & 7) << 6;
            const int bn_ = nblk << 6;
            const int wr = w >> 1, wc = w & 1;
            const int srow = tid >> 2, schunk = (tid & 3) << 4;
            const unsigned short* Ac = ctxb  + (size_t)(m0 + srow) * 512 + schunk;
            const unsigned short* Ah = hprev + (size_t)(m0 + srow) * 512 + schunk;
            const unsigned short* Bi = Wgi + (size_t)(bn_ + srow) * 512 + schunk;
            const unsigned short* Bh = Wgh + (size_t)(bn_ + srow) * 512 + schunk;
            uint4 ra0, ra1, rb0, rb1;
            f32x4 acc[2][2];
#pragma unroll
            for (int i = 0; i < 2; i++)
#pragma unroll
                for (int j = 0; j < 2; j++) acc[i][j] = f32x4{0.f, 0.f, 0.f, 0.f};
#define GLOADC(t) { const int tt = (t); \
            const unsigned short* ap = (tt < 8) ? Ac + (tt << 6) : Ah + ((tt - 8) << 6); \
            const unsigned short* bp = (tt < 8) ? Bi + (tt << 6) : Bh + ((tt - 8) << 6); \
            ra0 = *(const uint4*)ap; ra1 = *(const uint4*)(ap + 8); \
            rb0 = *(const uint4*)bp; rb1 = *(const uint4*)(bp + 8); }
#define WRITEBC(cb) { *(uint4*)&As[cb][srow][schunk] = ra0; *(uint4*)&As[cb][srow][schunk + 8] = ra1; \
                      *(uint4*)&Bs[cb][srow][schunk] = rb0; *(uint4*)&Bs[cb][srow][schunk + 8] = rb1; }
            GLOADC(0); WRITEBC(0);
            GLOADC(1);
            __syncthreads();
            for (int t = 0; t < 16; t++) {
                const int cb = t & 1;
                if (t + 1 < 16) WRITEBC(cb ^ 1);
                if (t + 2 < 16) GLOADC(t + 2);
                bf16x8 af[2][2], bfr[2][2];
#pragma unroll
                for (int fi = 0; fi < 2; fi++)
#pragma unroll
                    for (int ks = 0; ks < 2; ks++) {
                        af[fi][ks]  = *(const bf16x8*)&As[cb][(wr << 5) + (fi << 4) + fr][(ks << 5) + (fq << 3)];
                        bfr[fi][ks] = *(const bf16x8*)&Bs[cb][(wc << 5) + (fi << 4) + fr][(ks << 5) + (fq << 3)];
                    }
#pragma unroll
                for (int fi = 0; fi < 2; fi++)
#pragma unroll
                    for (int fj = 0; fj < 2; fj++)
#pragma unroll
                        for (int ks = 0; ks < 2; ks++)
                            acc[fi][fj] = __builtin_amdgcn_mfma_f32_16x16x32_bf16(
                                af[fi][ks], bfr[fj][ks], acc[fi][fj], 0, 0, 0);
                __syncthreads();
            }
#undef GLOADC
#undef WRITEBC
#pragma unroll
            for (int fi = 0; fi < 2; fi++)
#pragma unroll
                for (int fj = 0; fj < 2; fj++)
#pragma unroll
                    for (int r = 0; r < 4; r++)
                        gls[(wr << 5) + (fi << 4) + (fq << 2) + r][(wc << 5) + (fj << 4) + fr] = acc[fi][fj][r];
            __syncthreads();
            const int hbase = nblk << 4;
#pragma unroll
            for (int p = 0; p < 4; p++) {
                const int idx = (p << 8) + tid;
                const int ml = idx >> 4, hl = idx & 15;
                const int mg = m0 + ml, hg = hbase + hl;
                const int tok = text[mg * NS + s];
                const float4 gq = *(const float4*)&gls[ml][hl << 2];
                const float4 bq = *(const float4*)&bsum_p[bn_ + (hl << 2)];
                const float4 wq = *(const float4*)&Wtok_p[(size_t)tok * 2048 + bn_ + (hl << 2)];
                const float i_ = sigf(gq.x + bq.x + wq.x);
                const float f_ = sigf(gq.y + bq.y + wq.y);
                const float g_ = tanh_fast(gq.z + bq.z + wq.z);
                const float o_ = sigf(gq.w + bq.w + wq.w);
                const size_t ci = (size_t)mg * 512 + hg;
                const float cn = fmaf(f_, cst[ci], i_ * g_);
                cst[ci] = cn;
                const unsigned short hv = f2bf(o_ * tanh_fast(cn));
                hs[((size_t)mg * NS + s) * 512 + hg] = hv;
                hcur[ci] = hv;
            }
        }
        grid.sync();
    }
}

// ---------------------------------------------------------------------------
extern "C" void kernel_launch(void* const* d_in, const int* in_sizes, int n_in,
                              void* d_out, int out_size, void* d_ws, size_t ws_size,
                              hipStream_t stream) {
    const float* batch_H = (const float*)d_in[0];
    const int*   text    = (const int*)d_in[1];
    const float* W_i2h   = (const float*)d_in[2];
    const float* W_h2h   = (const float*)d_in[3];
    const float* b_h2h   = (const float*)d_in[4];
    const float* w_score = (const float*)d_in[5];
    const float* W_ih    = (const float*)d_in[6];
    const float* b_ih    = (const float*)d_in[7];
    const float* W_hh    = (const float*)d_in[8];
    const float* b_hh    = (const float*)d_in[9];
    const float* W_gen   = (const float*)d_in[10];
    const float* b_gen   = (const float*)d_in[11];
    float* out = (float*)d_out;

    char* wsp = (char*)d_ws;
    auto alloc = [&](size_t bytes) { char* p = wsp; wsp += (bytes + 255) & ~(size_t)255; return p; };
    unsigned short* bH    = (unsigned short*)alloc(32768ull * 512 * 2);
    unsigned short* Hproj = (unsigned short*)alloc(32768ull * 512 * 2);
    unsigned short* hs    = (unsigned short*)alloc(512ull * NS * 512 * 2);
    unsigned short* hbuf0 = (unsigned short*)alloc(512ull * 512 * 2);
    unsigned short* hbuf1 = (unsigned short*)alloc(512ull * 512 * 2);
    unsigned short* ctx   = (unsigned short*)alloc(512ull * 512 * 2);
    unsigned short* Wi2hb = (unsigned short*)alloc(512ull * 512 * 2);
    unsigned short* Wh2hb = (unsigned short*)alloc(512ull * 512 * 2);
    unsigned short* Wgi   = (unsigned short*)alloc(2048ull * 512 * 2);
    unsigned short* Wgh   = (unsigned short*)alloc(2048ull * 512 * 2);
    unsigned short* Wgenb = (unsigned short*)alloc(96ull * 512 * 2);
    float* ph     = (float*)alloc(512ull * 512 * 4);
    float* cst    = (float*)alloc(512ull * 512 * 4);
    float* bsum_p = (float*)alloc(2048ull * 4);
    float* Wtok_p = (float*)alloc(96ull * 2048 * 4);
    unsigned short* hb[2] = {hbuf0, hbuf1};

    hipMemsetAsync(hbuf1, 0, 512ull * 512 * 2, stream);
    hipMemsetAsync(cst, 0, 512ull * 512 * 4, stream);

    conv_f32_bf16<<<16384, 256, 0, stream>>>(batch_H, bH, 4194304);
    conv_f32_bf16<<<256, 256, 0, stream>>>(W_i2h, Wi2hb, 65536);
    conv_f32_bf16<<<256, 256, 0, stream>>>(W_h2h, Wh2hb, 65536);
    conv_f32_bf16<<<48, 256, 0, stream>>>(W_gen, Wgenb, 12288);
    conv_w_perm<<<512, 256, 0, stream>>>(W_ih, 608, Wgi);
    conv_w_perm<<<512, 256, 0, stream>>>(W_hh, 512, Wgh);
    conv_wtok<<<768, 256, 0, stream>>>(W_ih, Wtok_p);
    bias_perm<<<8, 256, 0, stream>>>(b_ih, b_hh, bsum_p);

    // H_proj = batch_H @ W_i2h^T -> bf16 [32768,512], XCD-swizzled
    gemm_bf16<0, 1><<<dim3(512, 8), 256, 0, stream>>>(bH, 512, Wi2hb, 512, Hproj, 512, nullptr, 512, 0);

    // Cooperative 26-step loop (R4-verbatim phases); fallback to R4 sequence on error.
    {
        void* params[16] = { (void*)&Hproj, (void*)&bH, (void*)&Wh2hb, (void*)&b_h2h,
                             (void*)&w_score, (void*)&Wgi, (void*)&Wgh, (void*)&bsum_p,
                             (void*)&Wtok_p, (void*)&text, (void*)&hbuf0, (void*)&hbuf1,
                             (void*)&ctx, (void*)&ph, (void*)&cst, (void*)&hs };
        hipError_t cerr = hipLaunchCooperativeKernel((void*)step_loop, dim3(512), dim3(256),
                                                     params, 0, stream);
        if (cerr != hipSuccess) {
            for (int s = 0; s < NS; ++s) {
                const unsigned short* hprev = hb[(s + 1) & 1];
                gemm_bf16<3, 0><<<dim3(8, 8), 256, 0, stream>>>(
                    hprev, 512, Wh2hb, 512, ph, 512, b_h2h, 512, 512);
                attn_kernel<<<512, 256, 0, stream>>>(Hproj, ph, w_score, bH, ctx);
                gates_lstm<<<dim3(32, 8), 256, 0, stream>>>(
                    ctx, hprev, Wgi, Wgh, bsum_p, Wtok_p, text, s, cst, hs, hb[s & 1]);
            }
        }
    }

    // out = hs @ W_gen^T + b_gen (f32, N=96 masked in 128-wide tiles)
    gemm_bf16<3, 0><<<dim3(2, 208), 256, 0, stream>>>(hs, 512, Wgenb, 512, out, 96, b_gen, 512, 96);
}

// Round 7
// 959.993 us; speedup vs baseline: 5.7453x; 5.7453x over previous
//
#include <hip/hip_runtime.h>
#include <cstddef>

#define NS 26

typedef short bf16x8 __attribute__((ext_vector_type(8)));
typedef float f32x4 __attribute__((ext_vector_type(4)));

__device__ __forceinline__ float tanh_fast(float x) { return 1.f - 2.f / (__expf(2.f * x) + 1.f); }
__device__ __forceinline__ float sigf(float x) { return 1.f / (1.f + __expf(-x)); }
__device__ __forceinline__ unsigned short f2bf(float x) {
    unsigned int u = __float_as_uint(x);
    return (unsigned short)((u + 0x7FFFu + ((u >> 16) & 1u)) >> 16);
}

// ---------------- batch_H convert ----------------
__global__ __launch_bounds__(256) void conv_f32_bf16(const float* __restrict__ s,
                                                     unsigned short* __restrict__ d, int n4) {
    int i = blockIdx.x * 256 + threadIdx.x;
    if (i >= n4) return;
    float4 v = ((const float4*)s)[i];
    ushort4 o; o.x = f2bf(v.x); o.y = f2bf(v.y); o.z = f2bf(v.z); o.w = f2bf(v.w);
    ((ushort4*)d)[i] = o;
}

// ---------------- merged weight setup (range-dispatched) ----------------
// blocks [0,256): W_i2h->Wi2hb | [256,512): W_h2h->Wh2hb | [512,560): W_gen->Wgenb
// [560,1072): W_ih->Wgi perm | [1072,1584): W_hh->Wgh perm | [1584,2352): Wtok_p
// [2352,2360): bsum_p
__global__ __launch_bounds__(256) void setup_all(
    const float* __restrict__ W_i2h, const float* __restrict__ W_h2h,
    const float* __restrict__ W_gen, const float* __restrict__ W_ih,
    const float* __restrict__ W_hh,  const float* __restrict__ b_ih,
    const float* __restrict__ b_hh,
    unsigned short* __restrict__ Wi2hb, unsigned short* __restrict__ Wh2hb,
    unsigned short* __restrict__ Wgenb, unsigned short* __restrict__ Wgi,
    unsigned short* __restrict__ Wgh,   float* __restrict__ Wtok_p,
    float* __restrict__ bsum_p)
{
    const int b = blockIdx.x, tid = threadIdx.x;
    if (b < 512) {            // plain f32->bf16 convert, 65536 float4 each
        const float* src = (b < 256) ? W_i2h : W_h2h;
        unsigned short* dst = (b < 256) ? Wi2hb : Wh2hb;
        const int i = ((b & 255) << 8) + tid;
        float4 v = ((const float4*)src)[i];
        ushort4 o; o.x = f2bf(v.x); o.y = f2bf(v.y); o.z = f2bf(v.z); o.w = f2bf(v.w);
        ((ushort4*)dst)[i] = o;
    } else if (b < 560) {     // W_gen 12288 float4
        const int i = ((b - 512) << 8) + tid;
        float4 v = ((const float4*)W_gen)[i];
        ushort4 o; o.x = f2bf(v.x); o.y = f2bf(v.y); o.z = f2bf(v.z); o.w = f2bf(v.w);
        ((ushort4*)Wgenb)[i] = o;
    } else if (b < 1584) {    // gate-permuted weights: n' = h*4+g
        const int isI = (b < 1072);
        const int i = ((b - (isI ? 560 : 1072)) << 8) + tid;   // [0,131072)
        const int np = i >> 6, k8 = (i & 63) << 3;
        const int h = np >> 2, g = np & 3;
        const float* p = (isI ? W_ih : W_hh) + (size_t)(g * 512 + h) * (isI ? 608 : 512) + k8;
        unsigned short* dst = isI ? Wgi : Wgh;
        float4 v0 = *(const float4*)p, v1 = *(const float4*)(p + 4);
        ushort4 o0, o1;
        o0.x = f2bf(v0.x); o0.y = f2bf(v0.y); o0.z = f2bf(v0.z); o0.w = f2bf(v0.w);
        o1.x = f2bf(v1.x); o1.y = f2bf(v1.y); o1.z = f2bf(v1.z); o1.w = f2bf(v1.w);
        *(ushort4*)(dst + (size_t)np * 512 + k8) = o0;
        *(ushort4*)(dst + (size_t)np * 512 + k8 + 4) = o1;
    } else if (b < 2352) {    // Wtok_p[t][n'] = W_ih[g*512+h][512+t]
        const int i = ((b - 1584) << 8) + tid;                 // [0,196608)
        const int t = i >> 11, np = i & 2047;
        const int h = np >> 2, g = np & 3;
        Wtok_p[i] = W_ih[(size_t)(g * 512 + h) * 608 + 512 + t];
    } else {                  // bsum_p
        const int i = ((b - 2352) << 8) + tid;                 // [0,2048)
        const int h = i >> 2, g = i & 3, n = g * 512 + h;
        bsum_p[i] = b_ih[n] + b_hh[n];
    }
}

// ---------------------------------------------------------------------------
// bf16 NT MFMA GEMM (proven R4 64x64). MODE 0: bf16 out. MODE 3: f32+bias masked.
// SWZ 1: H_proj XCD remap (grid dim3(512,8)).
// ---------------------------------------------------------------------------
template <int MODE, int SWZ>
__global__ __launch_bounds__(256) void gemm_bf16(
    const unsigned short* __restrict__ A, int lda,
    const unsigned short* __restrict__ B, int ldb,
    void* __restrict__ Cout, int ldc,
    const float* __restrict__ bias, int K, int Nreal)
{
    __shared__ unsigned short As[2][64][72];
    __shared__ unsigned short Bs[2][64][72];
    const int tid = threadIdx.x;
    int bm, bn;
    if (SWZ == 1) {
        const int l = blockIdx.x + (blockIdx.y << 9);
        const int cc = l & 7, k = l >> 3;
        bm = ((cc << 6) + (k >> 3)) << 6;
        bn = (k & 7) << 6;
    } else {
        bm = blockIdx.y << 6;
        bn = blockIdx.x << 6;
    }
    const int w = tid >> 6, lane = tid & 63;
    const int wr = w >> 1, wc = w & 1;
    const int srow = tid >> 2, schunk = (tid & 3) << 4;
    int brow = bn + srow;
    if (MODE == 3) brow = min(brow, Nreal - 1);
    const unsigned short* Ap = A + (size_t)(bm + srow) * lda + schunk;
    const unsigned short* Bp = B + (size_t)brow * ldb + schunk;
    const int fr = lane & 15, fq = lane >> 4;

    uint4 ra0, ra1, rb0, rb1;
    f32x4 acc[2][2];
#pragma unroll
    for (int i = 0; i < 2; i++)
#pragma unroll
        for (int j = 0; j < 2; j++) acc[i][j] = f32x4{0.f, 0.f, 0.f, 0.f};

    const int NTk = K >> 6;
#define LOADR(t) { ra0 = *(const uint4*)(Ap + ((t) << 6)); ra1 = *(const uint4*)(Ap + ((t) << 6) + 8); \
                   rb0 = *(const uint4*)(Bp + ((t) << 6)); rb1 = *(const uint4*)(Bp + ((t) << 6) + 8); }
#define WRITEB(cb) { *(uint4*)&As[cb][srow][schunk] = ra0; *(uint4*)&As[cb][srow][schunk + 8] = ra1; \
                     *(uint4*)&Bs[cb][srow][schunk] = rb0; *(uint4*)&Bs[cb][srow][schunk + 8] = rb1; }
    LOADR(0); WRITEB(0);
    LOADR(1);
    __syncthreads();
    for (int t = 0; t < NTk; t++) {
        const int cb = t & 1;
        if (t + 1 < NTk) WRITEB(cb ^ 1);
        if (t + 2 < NTk) LOADR(t + 2);
        bf16x8 af[2][2], bfr[2][2];
#pragma unroll
        for (int fi = 0; fi < 2; fi++)
#pragma unroll
            for (int ks = 0; ks < 2; ks++) {
                af[fi][ks]  = *(const bf16x8*)&As[cb][(wr << 5) + (fi << 4) + fr][(ks << 5) + (fq << 3)];
                bfr[fi][ks] = *(const bf16x8*)&Bs[cb][(wc << 5) + (fi << 4) + fr][(ks << 5) + (fq << 3)];
            }
#pragma unroll
        for (int fi = 0; fi < 2; fi++)
#pragma unroll
            for (int fj = 0; fj < 2; fj++)
#pragma unroll
                for (int ks = 0; ks < 2; ks++)
                    acc[fi][fj] = __builtin_amdgcn_mfma_f32_16x16x32_bf16(
                        af[fi][ks], bfr[fj][ks], acc[fi][fj], 0, 0, 0);
        __syncthreads();
    }
#undef LOADR
#undef WRITEB
#pragma unroll
    for (int fi = 0; fi < 2; fi++) {
        const int mbase = bm + (wr << 5) + (fi << 4) + (fq << 2);
#pragma unroll
        for (int fj = 0; fj < 2; fj++) {
            const int n = bn + (wc << 5) + (fj << 4) + fr;
            f32x4 v = acc[fi][fj];
            if (MODE == 0) {
                unsigned short* C = (unsigned short*)Cout;
#pragma unroll
                for (int r = 0; r < 4; r++) C[(size_t)(mbase + r) * ldc + n] = f2bf(v[r]);
            } else {
                if (n < Nreal) {
                    float* C = (float*)Cout;
                    const float bb = bias[n];
#pragma unroll
                    for (int r = 0; r < 4; r++) C[(size_t)(mbase + r) * ldc + n] = v[r] + bb;
                }
            }
        }
    }
}

// ---------------------------------------------------------------------------
// ph GEMM: 32x32 tiles, 256 blocks (grid 16x16 flattened), wave-per-quadrant.
// ph[m][n] = hprev[m][:] . Wh2h[n][:] + b_h2h[n], K=512.
// ---------------------------------------------------------------------------
__global__ __launch_bounds__(256) void gemm_ph(
    const unsigned short* __restrict__ A,   // hprev [512][512] bf16
    const unsigned short* __restrict__ B,   // Wh2hb [512][512] bf16
    float* __restrict__ C,                  // ph [512][512] f32
    const float* __restrict__ bias)
{
    __shared__ unsigned short As[2][32][72];
    __shared__ unsigned short Bs[2][32][72];
    const int tid = threadIdx.x;
    const int m0 = (blockIdx.x >> 4) << 5;
    const int n0 = (blockIdx.x & 15) << 5;
    const int w = tid >> 6, lane = tid & 63;
    const int fr = lane & 15, fq = lane >> 4;
    const int mf = w >> 1, nf = w & 1;
    const int srow = tid >> 3, schunk = (tid & 7) << 3;
    const unsigned short* Ap = A + (size_t)(m0 + srow) * 512 + schunk;
    const unsigned short* Bp = B + (size_t)(n0 + srow) * 512 + schunk;

    uint4 ra, rb;
    f32x4 acc = {0.f, 0.f, 0.f, 0.f};
    ra = *(const uint4*)Ap; rb = *(const uint4*)Bp;
    *(uint4*)&As[0][srow][schunk] = ra;
    *(uint4*)&Bs[0][srow][schunk] = rb;
    ra = *(const uint4*)(Ap + 64); rb = *(const uint4*)(Bp + 64);
    __syncthreads();
    for (int t = 0; t < 8; t++) {
        const int cb = t & 1;
        if (t + 1 < 8) { *(uint4*)&As[cb ^ 1][srow][schunk] = ra;
                         *(uint4*)&Bs[cb ^ 1][srow][schunk] = rb; }
        if (t + 2 < 8) { ra = *(const uint4*)(Ap + ((t + 2) << 6));
                         rb = *(const uint4*)(Bp + ((t + 2) << 6)); }
        const bf16x8 a0 = *(const bf16x8*)&As[cb][(mf << 4) + fr][(fq << 3)];
        const bf16x8 a1 = *(const bf16x8*)&As[cb][(mf << 4) + fr][32 + (fq << 3)];
        const bf16x8 b0 = *(const bf16x8*)&Bs[cb][(nf << 4) + fr][(fq << 3)];
        const bf16x8 b1 = *(const bf16x8*)&Bs[cb][(nf << 4) + fr][32 + (fq << 3)];
        acc = __builtin_amdgcn_mfma_f32_16x16x32_bf16(a0, b0, acc, 0, 0, 0);
        acc = __builtin_amdgcn_mfma_f32_16x16x32_bf16(a1, b1, acc, 0, 0, 0);
        __syncthreads();
    }
    const int n = n0 + (nf << 4) + fr;
    const float bb = bias[n];
#pragma unroll
    for (int r = 0; r < 4; r++)
        C[(size_t)(m0 + (mf << 4) + (fq << 2) + r) * 512 + n] = acc[r] + bb;
}

// ---------------------------------------------------------------------------
// Attention: ph/w hoisted into registers (no s_ph/s_w LDS, no bank conflicts).
// ---------------------------------------------------------------------------
__global__ __launch_bounds__(256) void attn_kernel(
    const unsigned short* __restrict__ H_proj,   // [B*64][512] bf16
    const float* __restrict__ ph,                // [B][512] f32
    const float* __restrict__ w_score,           // [512]
    const unsigned short* __restrict__ batch_H,  // [B*64][512] bf16
    unsigned short* __restrict__ ctx)            // [B][512] bf16
{
    __shared__ float s_e[64];
    __shared__ float s_al[64];
    const int b = blockIdx.x;
    const int tid = threadIdx.x;
    const int w = tid >> 6, lane = tid & 63;
    const int h0 = lane * 8;

    // hoist ph[b][h0..h0+8) and w[h0..h0+8) (t-invariant), coalesced 32B/lane
    const float4 p0 = *(const float4*)(ph + (size_t)b * 512 + h0);
    const float4 p1 = *(const float4*)(ph + (size_t)b * 512 + h0 + 4);
    const float4 w0 = *(const float4*)(w_score + h0);
    const float4 w1 = *(const float4*)(w_score + h0 + 4);
    const float rp[8] = {p0.x, p0.y, p0.z, p0.w, p1.x, p1.y, p1.z, p1.w};
    const float rw[8] = {w0.x, w0.y, w0.z, w0.w, w1.x, w1.y, w1.z, w1.w};

    for (int t = w; t < 64; t += 4) {
        const uint4 hv = *(const uint4*)(H_proj + ((size_t)b * 64 + t) * 512 + h0);
        unsigned int ua[4] = {hv.x, hv.y, hv.z, hv.w};
        float acc = 0.f;
#pragma unroll
        for (int j = 0; j < 4; j++) {
            const float e0 = __uint_as_float(ua[j] << 16);
            const float e1 = __uint_as_float(ua[j] & 0xffff0000u);
            acc += tanh_fast(e0 + rp[2 * j]) * rw[2 * j];
            acc += tanh_fast(e1 + rp[2 * j + 1]) * rw[2 * j + 1];
        }
#pragma unroll
        for (int off = 32; off; off >>= 1) acc += __shfl_xor(acc, off);
        if (lane == 0) s_e[t] = acc;
    }
    __syncthreads();
    if (tid < 64) {
        float m = -1e30f;
        for (int t = 0; t < 64; ++t) m = fmaxf(m, s_e[t]);
        float sum = 0.f;
        for (int t = 0; t < 64; ++t) sum += __expf(s_e[t] - m);
        s_al[tid] = __expf(s_e[tid] - m) / sum;
    }
    __syncthreads();
    const unsigned int* bHp = (const unsigned int*)(batch_H + (size_t)b * 64 * 512);
    float a0 = 0.f, a1 = 0.f;
    for (int t = 0; t < 64; ++t) {
        const unsigned int u = bHp[t * 256 + tid];
        const float al = s_al[t];
        a0 = fmaf(al, __uint_as_float(u << 16), a0);
        a1 = fmaf(al, __uint_as_float(u & 0xffff0000u), a1);
    }
    const unsigned int o = ((unsigned int)f2bf(a1) << 16) | (unsigned int)f2bf(a0);
    ((unsigned int*)(ctx + (size_t)b * 512))[tid] = o;
}

// ---------------------------------------------------------------------------
// Fused gates GEMM (gate-permuted N) + LSTM pointwise (proven R4).
// ---------------------------------------------------------------------------
__global__ __launch_bounds__(256) void gates_lstm(
    const unsigned short* __restrict__ ctx,
    const unsigned short* __restrict__ hprev,
    const unsigned short* __restrict__ Wgi,
    const unsigned short* __restrict__ Wgh,
    const float* __restrict__ bsum_p,
    const float* __restrict__ Wtok_p,
    const int* __restrict__ text, int sstep,
    float* __restrict__ c,
    unsigned short* __restrict__ hs,
    unsigned short* __restrict__ hnew)
{
    __shared__ __align__(16) char smem[36864];
    unsigned short (*As)[64][72] = (unsigned short(*)[64][72])smem;
    unsigned short (*Bs)[64][72] = (unsigned short(*)[64][72])(smem + 18432);
    float (*gls)[68] = (float(*)[68])smem;

    const int tid = threadIdx.x;
    const int l = blockIdx.x + (blockIdx.y << 5);
    const int cc = l & 7, kq = l >> 3;
    const int nblk = (cc << 2) + (kq >> 3);
    const int m0 = (kq & 7) << 6;
    const int bn_ = nblk << 6;
    const int w = tid >> 6, lane = tid & 63;
    const int wr = w >> 1, wc = w & 1;
    const int srow = tid >> 2, schunk = (tid & 3) << 4;
    const int fr = lane & 15, fq = lane >> 4;

    const unsigned short* Ac = ctx   + (size_t)(m0 + srow) * 512 + schunk;
    const unsigned short* Ah = hprev + (size_t)(m0 + srow) * 512 + schunk;
    const unsigned short* Bi = Wgi + (size_t)(bn_ + srow) * 512 + schunk;
    const unsigned short* Bh = Wgh + (size_t)(bn_ + srow) * 512 + schunk;

    uint4 ra0, ra1, rb0, rb1;
    f32x4 acc[2][2];
#pragma unroll
    for (int i = 0; i < 2; i++)
#pragma unroll
        for (int j = 0; j < 2; j++) acc[i][j] = f32x4{0.f, 0.f, 0.f, 0.f};

#define GLOAD(t) { const int tt = (t); \
    const unsigned short* ap = (tt < 8) ? Ac + (tt << 6) : Ah + ((tt - 8) << 6); \
    const unsigned short* bp = (tt < 8) ? Bi + (tt << 6) : Bh + ((tt - 8) << 6); \
    ra0 = *(const uint4*)ap; ra1 = *(const uint4*)(ap + 8); \
    rb0 = *(const uint4*)bp; rb1 = *(const uint4*)(bp + 8); }
#define WRITEB(cb) { *(uint4*)&As[cb][srow][schunk] = ra0; *(uint4*)&As[cb][srow][schunk + 8] = ra1; \
                     *(uint4*)&Bs[cb][srow][schunk] = rb0; *(uint4*)&Bs[cb][srow][schunk + 8] = rb1; }
    GLOAD(0); WRITEB(0);
    GLOAD(1);
    __syncthreads();
    for (int t = 0; t < 16; t++) {
        const int cb = t & 1;
        if (t + 1 < 16) WRITEB(cb ^ 1);
        if (t + 2 < 16) GLOAD(t + 2);
        bf16x8 af[2][2], bfr[2][2];
#pragma unroll
        for (int fi = 0; fi < 2; fi++)
#pragma unroll
            for (int ks = 0; ks < 2; ks++) {
                af[fi][ks]  = *(const bf16x8*)&As[cb][(wr << 5) + (fi << 4) + fr][(ks << 5) + (fq << 3)];
                bfr[fi][ks] = *(const bf16x8*)&Bs[cb][(wc << 5) + (fi << 4) + fr][(ks << 5) + (fq << 3)];
            }
#pragma unroll
        for (int fi = 0; fi < 2; fi++)
#pragma unroll
            for (int fj = 0; fj < 2; fj++)
#pragma unroll
                for (int ks = 0; ks < 2; ks++)
                    acc[fi][fj] = __builtin_amdgcn_mfma_f32_16x16x32_bf16(
                        af[fi][ks], bfr[fj][ks], acc[fi][fj], 0, 0, 0);
        __syncthreads();
    }
#undef GLOAD
#undef WRITEB
#pragma unroll
    for (int fi = 0; fi < 2; fi++)
#pragma unroll
        for (int fj = 0; fj < 2; fj++)
#pragma unroll
            for (int r = 0; r < 4; r++)
                gls[(wr << 5) + (fi << 4) + (fq << 2) + r][(wc << 5) + (fj << 4) + fr] = acc[fi][fj][r];
    __syncthreads();

    const int hbase = nblk << 4;
#pragma unroll
    for (int p = 0; p < 4; p++) {
        const int idx = (p << 8) + tid;
        const int ml = idx >> 4, hl = idx & 15;
        const int mg = m0 + ml, hg = hbase + hl;
        const int tok = text[mg * NS + sstep];
        const float4 gq = *(const float4*)&gls[ml][hl << 2];
        const float4 bq = *(const float4*)&bsum_p[bn_ + (hl << 2)];
        const float4 wq = *(const float4*)&Wtok_p[(size_t)tok * 2048 + bn_ + (hl << 2)];
        const float i_ = sigf(gq.x + bq.x + wq.x);
        const float f_ = sigf(gq.y + bq.y + wq.y);
        const float g_ = tanh_fast(gq.z + bq.z + wq.z);
        const float o_ = sigf(gq.w + bq.w + wq.w);
        const size_t ci = (size_t)mg * 512 + hg;
        const float cn = fmaf(f_, c[ci], i_ * g_);
        c[ci] = cn;
        const unsigned short hv = f2bf(o_ * tanh_fast(cn));
        hs[((size_t)mg * NS + sstep) * 512 + hg] = hv;
        hnew[ci] = hv;
    }
}

// ---------------------------------------------------------------------------
extern "C" void kernel_launch(void* const* d_in, const int* in_sizes, int n_in,
                              void* d_out, int out_size, void* d_ws, size_t ws_size,
                              hipStream_t stream) {
    const float* batch_H = (const float*)d_in[0];
    const int*   text    = (const int*)d_in[1];
    const float* W_i2h   = (const float*)d_in[2];
    const float* W_h2h   = (const float*)d_in[3];
    const float* b_h2h   = (const float*)d_in[4];
    const float* w_score = (const float*)d_in[5];
    const float* W_ih    = (const float*)d_in[6];
    const float* b_ih    = (const float*)d_in[7];
    const float* W_hh    = (const float*)d_in[8];
    const float* b_hh    = (const float*)d_in[9];
    const float* W_gen   = (const float*)d_in[10];
    const float* b_gen   = (const float*)d_in[11];
    float* out = (float*)d_out;

    char* wsp = (char*)d_ws;
    auto alloc = [&](size_t bytes) { char* p = wsp; wsp += (bytes + 255) & ~(size_t)255; return p; };
    unsigned short* bH    = (unsigned short*)alloc(32768ull * 512 * 2);
    unsigned short* Hproj = (unsigned short*)alloc(32768ull * 512 * 2);
    unsigned short* hs    = (unsigned short*)alloc(512ull * NS * 512 * 2);
    unsigned short* hbuf0 = (unsigned short*)alloc(512ull * 512 * 2);
    unsigned short* hbuf1 = (unsigned short*)alloc(512ull * 512 * 2);
    unsigned short* ctx   = (unsigned short*)alloc(512ull * 512 * 2);
    unsigned short* Wi2hb = (unsigned short*)alloc(512ull * 512 * 2);
    unsigned short* Wh2hb = (unsigned short*)alloc(512ull * 512 * 2);
    unsigned short* Wgi   = (unsigned short*)alloc(2048ull * 512 * 2);
    unsigned short* Wgh   = (unsigned short*)alloc(2048ull * 512 * 2);
    unsigned short* Wgenb = (unsigned short*)alloc(96ull * 512 * 2);
    float* ph     = (float*)alloc(512ull * 512 * 4);
    float* cst    = (float*)alloc(512ull * 512 * 4);
    float* bsum_p = (float*)alloc(2048ull * 4);
    float* Wtok_p = (float*)alloc(96ull * 2048 * 4);
    unsigned short* hb[2] = {hbuf0, hbuf1};

    hipMemsetAsync(hbuf1, 0, 512ull * 512 * 2, stream);
    hipMemsetAsync(cst, 0, 512ull * 512 * 4, stream);

    conv_f32_bf16<<<16384, 256, 0, stream>>>(batch_H, bH, 4194304);
    setup_all<<<2360, 256, 0, stream>>>(W_i2h, W_h2h, W_gen, W_ih, W_hh, b_ih, b_hh,
                                        Wi2hb, Wh2hb, Wgenb, Wgi, Wgh, Wtok_p, bsum_p);

    // H_proj = batch_H @ W_i2h^T -> bf16 [32768,512], XCD-swizzled
    gemm_bf16<0, 1><<<dim3(512, 8), 256, 0, stream>>>(bH, 512, Wi2hb, 512, Hproj, 512, nullptr, 512, 0);

    for (int s = 0; s < NS; ++s) {
        const unsigned short* hprev = hb[(s + 1) & 1];
        gemm_ph<<<256, 256, 0, stream>>>(hprev, Wh2hb, ph, b_h2h);
        attn_kernel<<<512, 256, 0, stream>>>(Hproj, ph, w_score, bH, ctx);
        gates_lstm<<<dim3(32, 8), 256, 0, stream>>>(
            ctx, hprev, Wgi, Wgh, bsum_p, Wtok_p, text, s, cst, hs, hb[s & 1]);
    }

    // out = hs @ W_gen^T + b_gen (f32, N=96 masked in 128-wide tiles)
    gemm_bf16<3, 0><<<dim3(2, 208), 256, 0, stream>>>(hs, 512, Wgenb, 512, out, 96, b_gen, 512, 96);
}